// Round 5
// baseline (137.614 us; speedup 1.0000x reference)
//
#include <hip/hip_runtime.h>

// BinaryConv2dSkip1x1 forward, MI355X — full-MFMA version, high-occupancy.
// out = RPReLU( conv3x3( sign(x+mb), sf*sign(w), pad=1 ) ) + conv1x1(x, skip_w) + skip_b
//
// Binary conv: sign bits expanded to +/-1 int8 planes in LDS (halo/out-of-bounds
// stored as 0 => exact zero padding), computed with mfma_i32_16x16x64_i8.
// Skip 1x1 conv: bf16 mfma_f32_16x16x32_bf16 over K=64 in two 32-ch passes.
// Round-5 changes: weight fragments (afrag) read from global/L2 instead of LDS
// (LDS 76.3 -> 39.2 KB => 4 blocks/CU for cross-block phase overlap), and an
// XCD-aware block swizzle (one batch image per XCD => halo reads hit L2).

#define HW (256*256)

typedef __bf16 bf16x8 __attribute__((ext_vector_type(8)));
typedef float  f32x4  __attribute__((ext_vector_type(4)));
typedef int    i32x4  __attribute__((ext_vector_type(4)));

__device__ __forceinline__ void lds_fence() {
    asm volatile("s_waitcnt lgkmcnt(0)" ::: "memory");
}

// expand 4 sign bits -> 4 i8 bytes (+1 for bit=0, -1 for bit=1)
__device__ __forceinline__ int expand4(unsigned int nib) {
    unsigned int spread = (nib * 0x00204081u) & 0x01010101u;  // bit i -> byte i LSB
    return (int)(0x01010101u ^ (spread * 0xFEu));             // 0x01 or 0xFF per byte
}

// ---------------- prep kernel: one block, 576 threads (o = tid/9, t = tid%9) ----------
__global__ void bq_prep_kernel(const float* __restrict__ weight,   // [64][64][3][3]
                               const float* __restrict__ pr_bias0,
                               const float* __restrict__ prelu_w,
                               const float* __restrict__ pr_bias1,
                               const float* __restrict__ skip_b,
                               const float* __restrict__ skipw,    // [64][64]
                               char* __restrict__ afrag,           // [4rt][9t][64 lane][16] i8
                               unsigned short* __restrict__ swfrag,// [4rt][2p][64 lane][8] bf16
                               float* __restrict__ consg) {        // [64][4]
    __shared__ float sabs_l[576];
    const int tid = threadIdx.x;
    const int o = tid / 9, t = tid % 9;
    const int m = o & 15, rt = o >> 4;
    float sabs = 0.f;
    for (int ch = 0; ch < 64; ++ch) {
        float wv = weight[(o*64 + ch)*9 + t];
        sabs += fabsf(wv);
        // lane l = m + 16*(ch>>4) holds A[m][k], k=(l>>4)*16 + (ch&15)
        afrag[((rt*9 + t)*64 + (m + 16*(ch >> 4)))*16 + (ch & 15)] =
            (wv < 0.f) ? (char)-1 : (char)1;
    }
    sabs_l[tid] = sabs;
    __syncthreads();
    if (t == 0) {
        float s = 0.f;
        #pragma unroll
        for (int k = 0; k < 9; ++k) s += sabs_l[o*9 + k];
        float sf = s / 576.f;
        consg[o*4 + 0] = sf;
        consg[o*4 + 1] = pr_bias0[o];
        consg[o*4 + 2] = prelu_w[o];
        consg[o*4 + 3] = pr_bias1[o] + skip_b[o];
    }
    if (t == 1) {
        for (int p = 0; p < 2; ++p)
            for (int gg = 0; gg < 4; ++gg)
                for (int i = 0; i < 8; ++i) {
                    float wv = skipw[o*64 + p*32 + gg*8 + i];
                    swfrag[((rt*2 + p)*64 + (m + 16*gg))*8 + i] =
                        __builtin_bit_cast(unsigned short, (__bf16)wv);
                }
    }
}

// ---------------- main kernel: tile 32 px x 8 rows, 512 threads (wave = one row) ------
__global__ __launch_bounds__(512, 6)
void bq_main_kernel(const float* __restrict__ x,        // [8][64][256][256]
                    const float* __restrict__ mb,       // [64]
                    const char* __restrict__ afrag,
                    const unsigned short* __restrict__ swfrag,
                    const float* __restrict__ consg,
                    float* __restrict__ out) {
    __shared__ __align__(16) char planes[10*4*34*16];          // 21760 B: [row][slot16ch][px][16]
    __shared__ __align__(16) unsigned short xslots[8*4*32*8];  // 16384 B: [wave][slot8ch][px][8bf16]
    __shared__ __align__(16) float cons[64*4];                 // 1024 B   => 39168 B total

    const int tid = threadIdx.x;
    const int l = tid & 63, w = tid >> 6;
    const int mypx = l & 31, chh = l >> 5;
    const int lg = l >> 4, lr = l & 15;

    // XCD swizzle: id -> vid so each XCD (id&7, assuming round-robin dispatch)
    // owns one batch image with row/col-neighbor tiles resident in its L2.
    const int id  = blockIdx.x;                 // 0..2047
    const int vid = (id & 7)*256 + (id >> 3);
    const int byp = vid & 31;                   // 0..31
    const int rest = vid >> 5;                  // 0..63
    const int bxp = rest & 7;                   // 0..7
    const int b   = rest >> 3;                  // 0..7

    const int h0 = byp*8 + w, px0 = bxp*32;
    const int pix = h0*256 + px0 + mypx;
    const float* xb = x + (size_t)b * 64 * HW;

    if (tid < 64) ((f32x4*)cons)[tid] = ((const f32x4*)consg)[tid];

    f32x4 skacc[4][2];
    #pragma unroll
    for (int rt = 0; rt < 4; ++rt)
        #pragma unroll
        for (int g = 0; g < 2; ++g) skacc[rt][g] = (f32x4){0.f, 0.f, 0.f, 0.f};

    // Phase A: two 32-ch passes. Each lane covers 16 ch of its pixel.
    unsigned int bits[2];
    #pragma unroll
    for (int p = 0; p < 2; ++p) {
        unsigned int bb = 0;
        bf16x8 v0, v1;
        #pragma unroll
        for (int j = 0; j < 16; ++j) {
            const int ch = p*32 + chh*16 + j;
            float xv = xb[(size_t)ch*HW + pix];
            bb |= (__float_as_uint(xv + mb[ch]) >> 31) << j;
            if (j < 8) v0[j] = (__bf16)xv; else v1[j-8] = (__bf16)xv;
        }
        bits[p] = bb;
        *(bf16x8*)&xslots[((w*4 + chh*2 + 0)*32 + mypx)*8] = v0;
        *(bf16x8*)&xslots[((w*4 + chh*2 + 1)*32 + mypx)*8] = v1;
        lds_fence();   // wave-synchronous: own wave's region
        bf16x8 bx[2];
        #pragma unroll
        for (int g = 0; g < 2; ++g)
            bx[g] = *(const bf16x8*)&xslots[((w*4 + lg)*32 + g*16 + lr)*8];
        #pragma unroll
        for (int rt = 0; rt < 4; ++rt) {
            bf16x8 sa = *(const bf16x8*)&swfrag[((rt*2 + p)*64 + l)*8];
            #pragma unroll
            for (int g = 0; g < 2; ++g)
                skacc[rt][g] = __builtin_amdgcn_mfma_f32_16x16x32_bf16(
                    sa, bx[g], skacc[rt][g], 0, 0, 0);
        }
        lds_fence();   // reads done before next pass overwrites
    }

    // Interior sign planes: slot s = chh + 2*p holds ch s*16..s*16+15 of this px.
    #pragma unroll
    for (int p = 0; p < 2; ++p) {
        const int s = chh + 2*p;
        i32x4 dw;
        dw[0] = expand4(bits[p] & 15);
        dw[1] = expand4((bits[p] >> 4) & 15);
        dw[2] = expand4((bits[p] >> 8) & 15);
        dw[3] = expand4((bits[p] >> 12) & 15);
        *(i32x4*)&planes[(((w + 1)*4 + s)*34 + mypx + 1)*16] = dw;
    }

    // Halo planes: 84 px (rows -1/+8, cols -1/+32) x 2 ch-halves = 168 jobs.
    if (tid < 168) {
        const int idx = tid >> 1, hh = tid & 1;
        int r, c;
        if (idx < 34)      { r = 0;        c = idx;      }
        else if (idx < 68) { r = 9;        c = idx - 34; }
        else if (idx < 76) { r = idx - 67; c = 0;        }   // r = 1..8
        else               { r = idx - 75; c = 33;       }   // r = 1..8
        const int hg = byp*8 + r - 1, wg = px0 + c - 1;
        const bool inb = (hg >= 0 && hg < 256 && wg >= 0 && wg < 256);
        #pragma unroll
        for (int p = 0; p < 2; ++p) {
            i32x4 dw = (i32x4){0, 0, 0, 0};          // OOB => 0 bytes = exact zero-pad
            if (inb) {
                unsigned int bb = 0;
                const int po = hg*256 + wg;
                #pragma unroll
                for (int j = 0; j < 16; ++j) {
                    const int ch = p*32 + hh*16 + j;
                    bb |= (__float_as_uint(xb[(size_t)ch*HW + po] + mb[ch]) >> 31) << j;
                }
                dw[0] = expand4(bb & 15);
                dw[1] = expand4((bb >> 4) & 15);
                dw[2] = expand4((bb >> 8) & 15);
                dw[3] = expand4((bb >> 12) & 15);
            }
            *(i32x4*)&planes[((r*4 + (hh + 2*p))*34 + c)*16] = dw;
        }
    }
    __syncthreads();

    // Phase C: binary conv via i8 MFMA (A-frags from global/L2) + fused epilogue.
    const int prow_base = ((w*4 + lg)*34 + lr)*16;
    float* outp = out + (size_t)b*64*HW + h0*256 + px0;

    #pragma unroll
    for (int rt = 0; rt < 4; ++rt) {
        i32x4 bacc0 = (i32x4){0,0,0,0}, bacc1 = (i32x4){0,0,0,0};
        #pragma unroll
        for (int t = 0; t < 9; ++t) {
            const int dr = t / 3, dc = t % 3;
            i32x4 a  = *(const i32x4*)&afrag[((rt*9 + t)*64 + l)*16];   // global, L2-hot
            i32x4 b0 = *(const i32x4*)&planes[prow_base + dr*(4*34*16) + dc*16];
            i32x4 b1 = *(const i32x4*)&planes[prow_base + dr*(4*34*16) + dc*16 + 256];
            bacc0 = __builtin_amdgcn_mfma_i32_16x16x64_i8(a, b0, bacc0, 0, 0, 0);
            bacc1 = __builtin_amdgcn_mfma_i32_16x16x64_i8(a, b1, bacc1, 0, 0, 0);
        }
        #pragma unroll
        for (int qi = 0; qi < 4; ++qi) {
            const int o = rt*16 + lg*4 + qi;
            f32x4 c4 = *(const f32x4*)&cons[o*4];   // (sf, pb0, aP, pb1+skip_b)
            {
                float tv = fmaf(c4[0], (float)bacc0[qi], c4[1]);
                tv = fmaxf(tv, 0.f) + c4[2]*fminf(tv, 0.f);
                outp[(size_t)o*HW + lr] = tv + c4[3] + skacc[rt][0][qi];
            }
            {
                float tv = fmaf(c4[0], (float)bacc1[qi], c4[1]);
                tv = fmaxf(tv, 0.f) + c4[2]*fminf(tv, 0.f);
                outp[(size_t)o*HW + 16 + lr] = tv + c4[3] + skacc[rt][1][qi];
            }
        }
    }
}

extern "C" void kernel_launch(void* const* d_in, const int* in_sizes, int n_in,
                              void* d_out, int out_size, void* d_ws, size_t ws_size,
                              hipStream_t stream) {
    const float* x      = (const float*)d_in[0];
    const float* mb     = (const float*)d_in[1];
    const float* weight = (const float*)d_in[2];
    const float* pb0    = (const float*)d_in[3];
    const float* pw     = (const float*)d_in[4];
    const float* pb1    = (const float*)d_in[5];
    const float* skw    = (const float*)d_in[6];
    const float* skb    = (const float*)d_in[7];
    float* out = (float*)d_out;

    char* ws = (char*)d_ws;
    char*           afrag  = ws;                               // 36864 B
    unsigned short* swfrag = (unsigned short*)(ws + 36864);    //  8192 B
    float*          consg  = (float*)(ws + 45056);             //  1024 B (total 46080)

    hipLaunchKernelGGL(bq_prep_kernel, dim3(1), dim3(576), 0, stream,
                       weight, pb0, pw, pb1, skb, skw, afrag, swfrag, consg);
    hipLaunchKernelGGL(bq_main_kernel, dim3(2048), dim3(512), 0, stream,
                       x, mb, afrag, swfrag, consg, out);
}

// Round 6
// 115.731 us; speedup vs baseline: 1.1891x; 1.1891x over previous
//
#include <hip/hip_runtime.h>

// BinaryConv2dSkip1x1 forward, MI355X — full-MFMA, small-LDS/high-occupancy.
// out = RPReLU( conv3x3( sign(x+mb), sf*sign(w), pad=1 ) ) + conv1x1(x, skip_w) + skip_b
//
// Binary conv: sign bits expanded to +/-1 int8 planes in LDS (halo/OOB stored 0
// => exact zero padding), computed with mfma_i32_16x16x64_i8.
// Skip 1x1 conv: bf16 mfma_f32_16x16x32_bf16 over K=64 in two 32-ch passes.
// Round-6: weight A-fragments kept PACKED (u16 sign bits) in LDS (5 KB) and
// expanded to +/-1 i8 in registers per tap; transient bf16 x-exchange buffer
// overlaid on the planes buffer (dead before planes written). LDS 76.3->27.9 KB
// => 3 blocks/CU, with all phase-C operands at LDS latency.

#define HW (256*256)

typedef __bf16 bf16x8 __attribute__((ext_vector_type(8)));
typedef float  f32x4  __attribute__((ext_vector_type(4)));
typedef int    i32x4  __attribute__((ext_vector_type(4)));

__device__ __forceinline__ void lds_fence() {
    asm volatile("s_waitcnt lgkmcnt(0)" ::: "memory");
}

// expand 4 sign bits -> 4 i8 bytes (+1 for bit=0, -1 for bit=1)
__device__ __forceinline__ int expand4(unsigned int nib) {
    unsigned int spread = (nib * 0x00204081u) & 0x01010101u;  // bit i -> byte i LSB
    return (int)(0x01010101u ^ (spread * 0xFEu));             // 0x01 or 0xFF per byte
}

// ---------------- prep kernel: one block, 576 threads (o = tid/9, t = tid%9) ----------
__global__ void bq_prep_kernel(const float* __restrict__ weight,   // [64][64][3][3]
                               const float* __restrict__ pr_bias0,
                               const float* __restrict__ prelu_w,
                               const float* __restrict__ pr_bias1,
                               const float* __restrict__ skip_b,
                               const float* __restrict__ skipw,    // [64][64]
                               unsigned short* __restrict__ abits, // [4rt][64 lane][10] u16
                               unsigned short* __restrict__ swfrag,// [4rt][2p][64 lane][8] bf16
                               float* __restrict__ consg) {        // [64][4]
    __shared__ float sabs_l[576];
    const int tid = threadIdx.x;
    const int o = tid / 9, t = tid % 9;
    const int m = o & 15, rt = o >> 4;
    unsigned short bg[4] = {0, 0, 0, 0};
    float sabs = 0.f;
    for (int ch = 0; ch < 64; ++ch) {
        float wv = weight[(o*64 + ch)*9 + t];
        sabs += fabsf(wv);
        if (wv < 0.f) bg[ch >> 4] |= (unsigned short)(1u << (ch & 15));
    }
    // lane l = m + 16*g holds A[m][k], k = g*16 + j; bit j of abits word = sign
    #pragma unroll
    for (int g = 0; g < 4; ++g)
        abits[(rt*64 + m + 16*g)*10 + t] = bg[g];
    sabs_l[tid] = sabs;
    __syncthreads();
    if (t == 0) {
        float s = 0.f;
        #pragma unroll
        for (int k = 0; k < 9; ++k) s += sabs_l[o*9 + k];
        float sf = s / 576.f;
        consg[o*4 + 0] = sf;
        consg[o*4 + 1] = pr_bias0[o];
        consg[o*4 + 2] = prelu_w[o];
        consg[o*4 + 3] = pr_bias1[o] + skip_b[o];
    }
    if (t == 1) {
        for (int p = 0; p < 2; ++p)
            for (int gg = 0; gg < 4; ++gg)
                for (int i = 0; i < 8; ++i) {
                    float wv = skipw[o*64 + p*32 + gg*8 + i];
                    swfrag[((rt*2 + p)*64 + (m + 16*gg))*8 + i] =
                        __builtin_bit_cast(unsigned short, (__bf16)wv);
                }
    }
}

// ---------------- main kernel: tile 32 px x 8 rows, 512 threads (wave = one row) ------
__global__ __launch_bounds__(512, 6)
void bq_main_kernel(const float* __restrict__ x,        // [8][64][256][256]
                    const float* __restrict__ mb,       // [64]
                    const unsigned short* __restrict__ abits_g,
                    const unsigned short* __restrict__ swfrag,
                    const float* __restrict__ consg,
                    float* __restrict__ out) {
    __shared__ __align__(16) char planes[10*4*34*16];      // 21760 B; first 16384 B double
                                                           // as bf16 xslots during phase A
    __shared__ __align__(16) unsigned short Abits[4*64*10];// 5120 B
    __shared__ __align__(16) float cons[64*4];             // 1024 B  => 27904 B total

    const int tid = threadIdx.x;
    const int l = tid & 63, w = tid >> 6;
    const int mypx = l & 31, chh = l >> 5;
    const int lg = l >> 4, lr = l & 15;

    // XCD swizzle: one batch image per XCD (id&7 = XCD under round-robin dispatch).
    const int id  = blockIdx.x;                 // 0..2047
    const int vid = (id & 7)*256 + (id >> 3);
    const int byp = vid & 31;                   // 0..31
    const int rest = vid >> 5;                  // 0..63
    const int bxp = rest & 7;                   // 0..7
    const int b   = rest >> 3;                  // 0..7

    const int h0 = byp*8 + w, px0 = bxp*32;
    const int pix = h0*256 + px0 + mypx;
    const float* xb = x + (size_t)b * 64 * HW;

    for (int i = tid; i < 1280; i += 512)
        ((unsigned int*)Abits)[i] = ((const unsigned int*)abits_g)[i];
    if (tid < 64) ((f32x4*)cons)[tid] = ((const f32x4*)consg)[tid];

    f32x4 skacc[4][2];
    #pragma unroll
    for (int rt = 0; rt < 4; ++rt)
        #pragma unroll
        for (int g = 0; g < 2; ++g) skacc[rt][g] = (f32x4){0.f, 0.f, 0.f, 0.f};

    // Phase A: two 32-ch passes. xslots overlays planes[0..16384).
    unsigned short* xsl = (unsigned short*)planes;
    unsigned int bits[2];
    #pragma unroll
    for (int p = 0; p < 2; ++p) {
        unsigned int bb = 0;
        bf16x8 v0, v1;
        #pragma unroll
        for (int j = 0; j < 16; ++j) {
            const int ch = p*32 + chh*16 + j;
            float xv = xb[(size_t)ch*HW + pix];
            bb |= (__float_as_uint(xv + mb[ch]) >> 31) << j;
            if (j < 8) v0[j] = (__bf16)xv; else v1[j-8] = (__bf16)xv;
        }
        bits[p] = bb;
        *(bf16x8*)&xsl[((w*4 + chh*2 + 0)*32 + mypx)*8] = v0;
        *(bf16x8*)&xsl[((w*4 + chh*2 + 1)*32 + mypx)*8] = v1;
        lds_fence();   // wave-synchronous: own wave's region
        bf16x8 bx[2];
        #pragma unroll
        for (int g = 0; g < 2; ++g)
            bx[g] = *(const bf16x8*)&xsl[((w*4 + lg)*32 + g*16 + lr)*8];
        #pragma unroll
        for (int rt = 0; rt < 4; ++rt) {
            bf16x8 sa = *(const bf16x8*)&swfrag[((rt*2 + p)*64 + l)*8];
            #pragma unroll
            for (int g = 0; g < 2; ++g)
                skacc[rt][g] = __builtin_amdgcn_mfma_f32_16x16x32_bf16(
                    sa, bx[g], skacc[rt][g], 0, 0, 0);
        }
        lds_fence();   // reads done before next pass overwrites
    }
    __syncthreads();   // all waves done with xslots overlay before planes written

    // Interior sign planes: slot s = chh + 2*p holds ch s*16..s*16+15 of this px.
    #pragma unroll
    for (int p = 0; p < 2; ++p) {
        const int s = chh + 2*p;
        i32x4 dw;
        dw[0] = expand4(bits[p] & 15);
        dw[1] = expand4((bits[p] >> 4) & 15);
        dw[2] = expand4((bits[p] >> 8) & 15);
        dw[3] = expand4((bits[p] >> 12) & 15);
        *(i32x4*)&planes[(((w + 1)*4 + s)*34 + mypx + 1)*16] = dw;
    }

    // Halo planes: 84 px (rows -1/+8, cols -1/+32) x 2 ch-halves = 168 jobs.
    if (tid < 168) {
        const int idx = tid >> 1, hh = tid & 1;
        int r, c;
        if (idx < 34)      { r = 0;        c = idx;      }
        else if (idx < 68) { r = 9;        c = idx - 34; }
        else if (idx < 76) { r = idx - 67; c = 0;        }   // r = 1..8
        else               { r = idx - 75; c = 33;       }   // r = 1..8
        const int hg = byp*8 + r - 1, wg = px0 + c - 1;
        const bool inb = (hg >= 0 && hg < 256 && wg >= 0 && wg < 256);
        #pragma unroll
        for (int p = 0; p < 2; ++p) {
            i32x4 dw = (i32x4){0, 0, 0, 0};          // OOB => 0 bytes = exact zero-pad
            if (inb) {
                unsigned int bb = 0;
                const int po = hg*256 + wg;
                #pragma unroll
                for (int j = 0; j < 16; ++j) {
                    const int ch = p*32 + hh*16 + j;
                    bb |= (__float_as_uint(xb[(size_t)ch*HW + po] + mb[ch]) >> 31) << j;
                }
                dw[0] = expand4(bb & 15);
                dw[1] = expand4((bb >> 4) & 15);
                dw[2] = expand4((bb >> 8) & 15);
                dw[3] = expand4((bb >> 12) & 15);
            }
            *(i32x4*)&planes[((r*4 + (hh + 2*p))*34 + c)*16] = dw;
        }
    }
    __syncthreads();

    // Phase C: binary conv via i8 MFMA; A expanded from packed bits per tap.
    const int prow_base = ((w*4 + lg)*34 + lr)*16;
    float* outp = out + (size_t)b*64*HW + h0*256 + px0;

    #pragma unroll
    for (int rt = 0; rt < 4; ++rt) {
        // this lane's packed A row: 5 dwords, stride 20 B (bank-conflict-free)
        const unsigned int* arow = (const unsigned int*)&Abits[(rt*64 + l)*10];
        unsigned int ad[5];
        #pragma unroll
        for (int k = 0; k < 5; ++k) ad[k] = arow[k];

        i32x4 bacc0 = (i32x4){0,0,0,0}, bacc1 = (i32x4){0,0,0,0};
        #pragma unroll
        for (int t = 0; t < 9; ++t) {
            const int dr = t / 3, dc = t % 3;
            const unsigned int tb = (ad[t >> 1] >> ((t & 1)*16)) & 0xffffu;
            i32x4 a;
            a[0] = expand4(tb & 15);
            a[1] = expand4((tb >> 4) & 15);
            a[2] = expand4((tb >> 8) & 15);
            a[3] = expand4((tb >> 12) & 15);
            i32x4 b0 = *(const i32x4*)&planes[prow_base + dr*(4*34*16) + dc*16];
            i32x4 b1 = *(const i32x4*)&planes[prow_base + dr*(4*34*16) + dc*16 + 256];
            bacc0 = __builtin_amdgcn_mfma_i32_16x16x64_i8(a, b0, bacc0, 0, 0, 0);
            bacc1 = __builtin_amdgcn_mfma_i32_16x16x64_i8(a, b1, bacc1, 0, 0, 0);
        }
        #pragma unroll
        for (int qi = 0; qi < 4; ++qi) {
            const int o = rt*16 + lg*4 + qi;
            f32x4 c4 = *(const f32x4*)&cons[o*4];   // (sf, pb0, aP, pb1+skip_b)
            {
                float tv = fmaf(c4[0], (float)bacc0[qi], c4[1]);
                tv = fmaxf(tv, 0.f) + c4[2]*fminf(tv, 0.f);
                outp[(size_t)o*HW + lr] = tv + c4[3] + skacc[rt][0][qi];
            }
            {
                float tv = fmaf(c4[0], (float)bacc1[qi], c4[1]);
                tv = fmaxf(tv, 0.f) + c4[2]*fminf(tv, 0.f);
                outp[(size_t)o*HW + 16 + lr] = tv + c4[3] + skacc[rt][1][qi];
            }
        }
    }
}

extern "C" void kernel_launch(void* const* d_in, const int* in_sizes, int n_in,
                              void* d_out, int out_size, void* d_ws, size_t ws_size,
                              hipStream_t stream) {
    const float* x      = (const float*)d_in[0];
    const float* mb     = (const float*)d_in[1];
    const float* weight = (const float*)d_in[2];
    const float* pb0    = (const float*)d_in[3];
    const float* pw     = (const float*)d_in[4];
    const float* pb1    = (const float*)d_in[5];
    const float* skw    = (const float*)d_in[6];
    const float* skb    = (const float*)d_in[7];
    float* out = (float*)d_out;

    char* ws = (char*)d_ws;
    unsigned short* abits  = (unsigned short*)ws;              // 5120 B
    unsigned short* swfrag = (unsigned short*)(ws + 5120);     // 8192 B
    float*          consg  = (float*)(ws + 13312);             // 1024 B (total 14336)

    hipLaunchKernelGGL(bq_prep_kernel, dim3(1), dim3(576), 0, stream,
                       weight, pb0, pw, pb1, skb, skw, abits, swfrag, consg);
    hipLaunchKernelGGL(bq_main_kernel, dim3(2048), dim3(512), 0, stream,
                       x, mb, abits, swfrag, consg, out);
}

// Round 7
// 109.265 us; speedup vs baseline: 1.2595x; 1.0592x over previous
//
#include <hip/hip_runtime.h>

// BinaryConv2dSkip1x1 forward, MI355X — full-MFMA, small-LDS/high-occupancy.
// out = RPReLU( conv3x3( sign(x+mb), sf*sign(w), pad=1 ) ) + conv1x1(x, skip_w) + skip_b
//
// Binary conv: sign bits expanded to +/-1 int8 planes in LDS (halo/OOB stored 0
// => exact zero padding), computed with mfma_i32_16x16x64_i8.
// Skip 1x1 conv: bf16 mfma_f32_16x16x32_bf16 over K=64 in two 32-ch passes.
// Round-7: launch_bounds back to (512,4) — round 6's (512,6) capped VGPRs at 40
// and spilled skacc to scratch (+53 MB WRITE_SIZE of hidden traffic). Structure
// otherwise identical to round 6 (packed A-bits in LDS, xslots overlaid on
// planes, 27.9 KB LDS, XCD swizzle).

#define HW (256*256)

typedef __bf16 bf16x8 __attribute__((ext_vector_type(8)));
typedef float  f32x4  __attribute__((ext_vector_type(4)));
typedef int    i32x4  __attribute__((ext_vector_type(4)));

__device__ __forceinline__ void lds_fence() {
    asm volatile("s_waitcnt lgkmcnt(0)" ::: "memory");
}

// expand 4 sign bits -> 4 i8 bytes (+1 for bit=0, -1 for bit=1)
__device__ __forceinline__ int expand4(unsigned int nib) {
    unsigned int spread = (nib * 0x00204081u) & 0x01010101u;  // bit i -> byte i LSB
    return (int)(0x01010101u ^ (spread * 0xFEu));             // 0x01 or 0xFF per byte
}

// ---------------- prep kernel: one block, 576 threads (o = tid/9, t = tid%9) ----------
__global__ void bq_prep_kernel(const float* __restrict__ weight,   // [64][64][3][3]
                               const float* __restrict__ pr_bias0,
                               const float* __restrict__ prelu_w,
                               const float* __restrict__ pr_bias1,
                               const float* __restrict__ skip_b,
                               const float* __restrict__ skipw,    // [64][64]
                               unsigned short* __restrict__ abits, // [4rt][64 lane][10] u16
                               unsigned short* __restrict__ swfrag,// [4rt][2p][64 lane][8] bf16
                               float* __restrict__ consg) {        // [64][4]
    __shared__ float sabs_l[576];
    const int tid = threadIdx.x;
    const int o = tid / 9, t = tid % 9;
    const int m = o & 15, rt = o >> 4;
    unsigned short bg[4] = {0, 0, 0, 0};
    float sabs = 0.f;
    for (int ch = 0; ch < 64; ++ch) {
        float wv = weight[(o*64 + ch)*9 + t];
        sabs += fabsf(wv);
        if (wv < 0.f) bg[ch >> 4] |= (unsigned short)(1u << (ch & 15));
    }
    // lane l = m + 16*g holds A[m][k], k = g*16 + j; bit j of abits word = sign
    #pragma unroll
    for (int g = 0; g < 4; ++g)
        abits[(rt*64 + m + 16*g)*10 + t] = bg[g];
    sabs_l[tid] = sabs;
    __syncthreads();
    if (t == 0) {
        float s = 0.f;
        #pragma unroll
        for (int k = 0; k < 9; ++k) s += sabs_l[o*9 + k];
        float sf = s / 576.f;
        consg[o*4 + 0] = sf;
        consg[o*4 + 1] = pr_bias0[o];
        consg[o*4 + 2] = prelu_w[o];
        consg[o*4 + 3] = pr_bias1[o] + skip_b[o];
    }
    if (t == 1) {
        for (int p = 0; p < 2; ++p)
            for (int gg = 0; gg < 4; ++gg)
                for (int i = 0; i < 8; ++i) {
                    float wv = skipw[o*64 + p*32 + gg*8 + i];
                    swfrag[((rt*2 + p)*64 + (m + 16*gg))*8 + i] =
                        __builtin_bit_cast(unsigned short, (__bf16)wv);
                }
    }
}

// ---------------- main kernel: tile 32 px x 8 rows, 512 threads (wave = one row) ------
__global__ __launch_bounds__(512, 4)
void bq_main_kernel(const float* __restrict__ x,        // [8][64][256][256]
                    const float* __restrict__ mb,       // [64]
                    const unsigned short* __restrict__ abits_g,
                    const unsigned short* __restrict__ swfrag,
                    const float* __restrict__ consg,
                    float* __restrict__ out) {
    __shared__ __align__(16) char planes[10*4*34*16];      // 21760 B; first 16384 B double
                                                           // as bf16 xslots during phase A
    __shared__ __align__(16) unsigned short Abits[4*64*10];// 5120 B
    __shared__ __align__(16) float cons[64*4];             // 1024 B  => 27904 B total

    const int tid = threadIdx.x;
    const int l = tid & 63, w = tid >> 6;
    const int mypx = l & 31, chh = l >> 5;
    const int lg = l >> 4, lr = l & 15;

    // XCD swizzle: one batch image per XCD (id&7 = XCD under round-robin dispatch).
    const int id  = blockIdx.x;                 // 0..2047
    const int vid = (id & 7)*256 + (id >> 3);
    const int byp = vid & 31;                   // 0..31
    const int rest = vid >> 5;                  // 0..63
    const int bxp = rest & 7;                   // 0..7
    const int b   = rest >> 3;                  // 0..7

    const int h0 = byp*8 + w, px0 = bxp*32;
    const int pix = h0*256 + px0 + mypx;
    const float* xb = x + (size_t)b * 64 * HW;

    for (int i = tid; i < 1280; i += 512)
        ((unsigned int*)Abits)[i] = ((const unsigned int*)abits_g)[i];
    if (tid < 64) ((f32x4*)cons)[tid] = ((const f32x4*)consg)[tid];

    f32x4 skacc[4][2];
    #pragma unroll
    for (int rt = 0; rt < 4; ++rt)
        #pragma unroll
        for (int g = 0; g < 2; ++g) skacc[rt][g] = (f32x4){0.f, 0.f, 0.f, 0.f};

    // Phase A: two 32-ch passes. xslots overlays planes[0..16384).
    unsigned short* xsl = (unsigned short*)planes;
    unsigned int bits[2];
    #pragma unroll
    for (int p = 0; p < 2; ++p) {
        unsigned int bb = 0;
        bf16x8 v0, v1;
        #pragma unroll
        for (int j = 0; j < 16; ++j) {
            const int ch = p*32 + chh*16 + j;
            float xv = xb[(size_t)ch*HW + pix];
            bb |= (__float_as_uint(xv + mb[ch]) >> 31) << j;
            if (j < 8) v0[j] = (__bf16)xv; else v1[j-8] = (__bf16)xv;
        }
        bits[p] = bb;
        *(bf16x8*)&xsl[((w*4 + chh*2 + 0)*32 + mypx)*8] = v0;
        *(bf16x8*)&xsl[((w*4 + chh*2 + 1)*32 + mypx)*8] = v1;
        lds_fence();   // wave-synchronous: own wave's region
        bf16x8 bx[2];
        #pragma unroll
        for (int g = 0; g < 2; ++g)
            bx[g] = *(const bf16x8*)&xsl[((w*4 + lg)*32 + g*16 + lr)*8];
        #pragma unroll
        for (int rt = 0; rt < 4; ++rt) {
            bf16x8 sa = *(const bf16x8*)&swfrag[((rt*2 + p)*64 + l)*8];
            #pragma unroll
            for (int g = 0; g < 2; ++g)
                skacc[rt][g] = __builtin_amdgcn_mfma_f32_16x16x32_bf16(
                    sa, bx[g], skacc[rt][g], 0, 0, 0);
        }
        lds_fence();   // reads done before next pass overwrites
    }
    __syncthreads();   // all waves done with xslots overlay before planes written

    // Interior sign planes: slot s = chh + 2*p holds ch s*16..s*16+15 of this px.
    #pragma unroll
    for (int p = 0; p < 2; ++p) {
        const int s = chh + 2*p;
        i32x4 dw;
        dw[0] = expand4(bits[p] & 15);
        dw[1] = expand4((bits[p] >> 4) & 15);
        dw[2] = expand4((bits[p] >> 8) & 15);
        dw[3] = expand4((bits[p] >> 12) & 15);
        *(i32x4*)&planes[(((w + 1)*4 + s)*34 + mypx + 1)*16] = dw;
    }

    // Halo planes: 84 px (rows -1/+8, cols -1/+32) x 2 ch-halves = 168 jobs.
    if (tid < 168) {
        const int idx = tid >> 1, hh = tid & 1;
        int r, c;
        if (idx < 34)      { r = 0;        c = idx;      }
        else if (idx < 68) { r = 9;        c = idx - 34; }
        else if (idx < 76) { r = idx - 67; c = 0;        }   // r = 1..8
        else               { r = idx - 75; c = 33;       }   // r = 1..8
        const int hg = byp*8 + r - 1, wg = px0 + c - 1;
        const bool inb = (hg >= 0 && hg < 256 && wg >= 0 && wg < 256);
        #pragma unroll
        for (int p = 0; p < 2; ++p) {
            i32x4 dw = (i32x4){0, 0, 0, 0};          // OOB => 0 bytes = exact zero-pad
            if (inb) {
                unsigned int bb = 0;
                const int po = hg*256 + wg;
                #pragma unroll
                for (int j = 0; j < 16; ++j) {
                    const int ch = p*32 + hh*16 + j;
                    bb |= (__float_as_uint(xb[(size_t)ch*HW + po] + mb[ch]) >> 31) << j;
                }
                dw[0] = expand4(bb & 15);
                dw[1] = expand4((bb >> 4) & 15);
                dw[2] = expand4((bb >> 8) & 15);
                dw[3] = expand4((bb >> 12) & 15);
            }
            *(i32x4*)&planes[((r*4 + (hh + 2*p))*34 + c)*16] = dw;
        }
    }
    __syncthreads();

    // Phase C: binary conv via i8 MFMA; A expanded from packed bits per tap.
    const int prow_base = ((w*4 + lg)*34 + lr)*16;
    float* outp = out + (size_t)b*64*HW + h0*256 + px0;

    #pragma unroll
    for (int rt = 0; rt < 4; ++rt) {
        // this lane's packed A row: 5 dwords, stride 20 B (bank-conflict-free)
        const unsigned int* arow = (const unsigned int*)&Abits[(rt*64 + l)*10];
        unsigned int ad[5];
        #pragma unroll
        for (int k = 0; k < 5; ++k) ad[k] = arow[k];

        i32x4 bacc0 = (i32x4){0,0,0,0}, bacc1 = (i32x4){0,0,0,0};
        #pragma unroll
        for (int t = 0; t < 9; ++t) {
            const int dr = t / 3, dc = t % 3;
            const unsigned int tb = (ad[t >> 1] >> ((t & 1)*16)) & 0xffffu;
            i32x4 a;
            a[0] = expand4(tb & 15);
            a[1] = expand4((tb >> 4) & 15);
            a[2] = expand4((tb >> 8) & 15);
            a[3] = expand4((tb >> 12) & 15);
            i32x4 b0 = *(const i32x4*)&planes[prow_base + dr*(4*34*16) + dc*16];
            i32x4 b1 = *(const i32x4*)&planes[prow_base + dr*(4*34*16) + dc*16 + 256];
            bacc0 = __builtin_amdgcn_mfma_i32_16x16x64_i8(a, b0, bacc0, 0, 0, 0);
            bacc1 = __builtin_amdgcn_mfma_i32_16x16x64_i8(a, b1, bacc1, 0, 0, 0);
        }
        #pragma unroll
        for (int qi = 0; qi < 4; ++qi) {
            const int o = rt*16 + lg*4 + qi;
            f32x4 c4 = *(const f32x4*)&cons[o*4];   // (sf, pb0, aP, pb1+skip_b)
            {
                float tv = fmaf(c4[0], (float)bacc0[qi], c4[1]);
                tv = fmaxf(tv, 0.f) + c4[2]*fminf(tv, 0.f);
                outp[(size_t)o*HW + lr] = tv + c4[3] + skacc[rt][0][qi];
            }
            {
                float tv = fmaf(c4[0], (float)bacc1[qi], c4[1]);
                tv = fmaxf(tv, 0.f) + c4[2]*fminf(tv, 0.f);
                outp[(size_t)o*HW + 16 + lr] = tv + c4[3] + skacc[rt][1][qi];
            }
        }
    }
}

extern "C" void kernel_launch(void* const* d_in, const int* in_sizes, int n_in,
                              void* d_out, int out_size, void* d_ws, size_t ws_size,
                              hipStream_t stream) {
    const float* x      = (const float*)d_in[0];
    const float* mb     = (const float*)d_in[1];
    const float* weight = (const float*)d_in[2];
    const float* pb0    = (const float*)d_in[3];
    const float* pw     = (const float*)d_in[4];
    const float* pb1    = (const float*)d_in[5];
    const float* skw    = (const float*)d_in[6];
    const float* skb    = (const float*)d_in[7];
    float* out = (float*)d_out;

    char* ws = (char*)d_ws;
    unsigned short* abits  = (unsigned short*)ws;              // 5120 B
    unsigned short* swfrag = (unsigned short*)(ws + 5120);     // 8192 B
    float*          consg  = (float*)(ws + 13312);             // 1024 B (total 14336)

    hipLaunchKernelGGL(bq_prep_kernel, dim3(1), dim3(576), 0, stream,
                       weight, pb0, pw, pb1, skb, skw, abits, swfrag, consg);
    hipLaunchKernelGGL(bq_main_kernel, dim3(2048), dim3(512), 0, stream,
                       x, mb, abits, swfrag, consg, out);
}

// Round 9
// 98.001 us; speedup vs baseline: 1.4042x; 1.1149x over previous
//
#include <hip/hip_runtime.h>

// BinaryConv2dSkip1x1 forward, MI355X — full-MFMA, spill-free, wide-load version.
// out = RPReLU( conv3x3( sign(x+mb), sf*sign(w), pad=1 ) ) + conv1x1(x, skip_w) + skip_b
//
// Binary conv: sign bits expanded to +/-1 int8 planes in LDS (halo/OOB stored 0
// => exact zero padding), computed with mfma_i32_16x16x64_i8.
// Skip 1x1 conv: bf16 mfma_f32_16x16x32_bf16 over K=64.
// Round-9: round-8 with the compile fix (lq_dummy removed; lg used directly).
// (a) launch_bounds (512,2) — (512,4) capped VGPRs at 64 and spilled ~9 regs
// (+75 MB hidden HBM traffic, seen as WRITE_SIZE 168 vs 131 MB).
// (b) x loaded as 8x float4 per lane (4 px x 8 consecutive ch) instead of 32
// scalar dwords; per-pixel u64 sign words built with a 3-step shfl_xor OR tree;
// bf16 B-frag exchange through the overlaid LDS buffer in two 16-px passes.

#define HW (256*256)

typedef __bf16 bf16x8 __attribute__((ext_vector_type(8)));
typedef float  f32x4  __attribute__((ext_vector_type(4)));
typedef int    i32x4  __attribute__((ext_vector_type(4)));

__device__ __forceinline__ void lds_fence() {
    asm volatile("s_waitcnt lgkmcnt(0)" ::: "memory");
}

// expand 4 sign bits -> 4 i8 bytes (+1 for bit=0, -1 for bit=1)
__device__ __forceinline__ int expand4(unsigned int nib) {
    unsigned int spread = (nib * 0x00204081u) & 0x01010101u;  // bit i -> byte i LSB
    return (int)(0x01010101u ^ (spread * 0xFEu));             // 0x01 or 0xFF per byte
}

// ---------------- prep kernel: one block, 576 threads (o = tid/9, t = tid%9) ----------
__global__ void bq_prep_kernel(const float* __restrict__ weight,   // [64][64][3][3]
                               const float* __restrict__ pr_bias0,
                               const float* __restrict__ prelu_w,
                               const float* __restrict__ pr_bias1,
                               const float* __restrict__ skip_b,
                               const float* __restrict__ skipw,    // [64][64]
                               unsigned short* __restrict__ abits, // [4rt][64 lane][10] u16
                               unsigned short* __restrict__ swfrag,// [4rt][2p][64 lane][8] bf16
                               float* __restrict__ consg) {        // [64][4]
    __shared__ float sabs_l[576];
    const int tid = threadIdx.x;
    const int o = tid / 9, t = tid % 9;
    const int m = o & 15, rt = o >> 4;
    unsigned short bg[4] = {0, 0, 0, 0};
    float sabs = 0.f;
    for (int ch = 0; ch < 64; ++ch) {
        float wv = weight[(o*64 + ch)*9 + t];
        sabs += fabsf(wv);
        if (wv < 0.f) bg[ch >> 4] |= (unsigned short)(1u << (ch & 15));
    }
    // lane l = m + 16*g holds A[m][k], k = g*16 + j; bit j of abits word = sign
    #pragma unroll
    for (int g = 0; g < 4; ++g)
        abits[(rt*64 + m + 16*g)*10 + t] = bg[g];
    sabs_l[tid] = sabs;
    __syncthreads();
    if (t == 0) {
        float s = 0.f;
        #pragma unroll
        for (int k = 0; k < 9; ++k) s += sabs_l[o*9 + k];
        float sf = s / 576.f;
        consg[o*4 + 0] = sf;
        consg[o*4 + 1] = pr_bias0[o];
        consg[o*4 + 2] = prelu_w[o];
        consg[o*4 + 3] = pr_bias1[o] + skip_b[o];
    }
    if (t == 1) {
        for (int p = 0; p < 2; ++p)
            for (int gg = 0; gg < 4; ++gg)
                for (int i = 0; i < 8; ++i) {
                    float wv = skipw[o*64 + p*32 + gg*8 + i];
                    swfrag[((rt*2 + p)*64 + (m + 16*gg))*8 + i] =
                        __builtin_bit_cast(unsigned short, (__bf16)wv);
                }
    }
}

// ---------------- main kernel: tile 32 px x 8 rows, 512 threads (wave = one row) ------
__global__ __launch_bounds__(512, 2)
void bq_main_kernel(const float* __restrict__ x,        // [8][64][256][256]
                    const float* __restrict__ mb,       // [64]
                    const unsigned short* __restrict__ abits_g,
                    const unsigned short* __restrict__ swfrag,
                    const float* __restrict__ consg,
                    float* __restrict__ out) {
    __shared__ __align__(16) char planes[10*4*34*16];      // 21760 B; first 16 KB double as
                                                           // per-wave bf16 exchange (2 KB/wave)
    __shared__ __align__(16) unsigned short Abits[4*64*10];// 5120 B
    __shared__ __align__(16) float cons[64*4];             // 1024 B  => 27904 B total

    const int tid = threadIdx.x;
    const int l = tid & 63, w = tid >> 6;
    const int pxg = l & 7,  chg = l >> 3;   // 4-px group / 8-ch group
    const int lg = l >> 4,  lr = l & 15;

    // XCD swizzle: one batch image per XCD (id&7 = XCD under round-robin dispatch).
    const int id  = blockIdx.x;                 // 0..2047
    const int vid = (id & 7)*256 + (id >> 3);
    const int byp = vid & 31;                   // 0..31
    const int rest = vid >> 5;                  // 0..63
    const int bxp = rest & 7;                   // 0..7
    const int b   = rest >> 3;                  // 0..7

    const int h0 = byp*8 + w, px0 = bxp*32;
    const float* xb = x + (size_t)b * 64 * HW;

    for (int i = tid; i < 1280; i += 512)
        ((unsigned int*)Abits)[i] = ((const unsigned int*)abits_g)[i];
    if (tid < 64) ((f32x4*)cons)[tid] = ((const f32x4*)consg)[tid];

    f32x4 skacc[4][2];
    #pragma unroll
    for (int rt = 0; rt < 4; ++rt)
        #pragma unroll
        for (int g = 0; g < 2; ++g) skacc[rt][g] = (f32x4){0.f, 0.f, 0.f, 0.f};

    // ---- Phase A: wide loads. Lane covers 4 px (pxg*4..+3) x 8 ch (chg*8..+7).
    const f32x4* xrow = (const f32x4*)(xb + (size_t)(chg*8)*HW + h0*256 + px0 + pxg*4);
    f32x4 v[8];
    #pragma unroll
    for (int i = 0; i < 8; ++i) v[i] = xrow[(size_t)i*(HW/4)];
    f32x4 m0 = *(const f32x4*)&mb[chg*8];
    f32x4 m1 = *(const f32x4*)&mb[chg*8 + 4];

    unsigned long long sb0, sb1, sb2, sb3;   // per-px sign words (named: no dyn indexing)
    bf16x8 pk[4];
    {
        unsigned int by[4];
        #pragma unroll
        for (int e = 0; e < 4; ++e) {
            unsigned int bb = 0;
            #pragma unroll
            for (int i = 0; i < 8; ++i) {
                float xv = v[i][e];
                float mm = (i < 4) ? m0[i] : m1[i-4];
                bb |= (__float_as_uint(xv + mm) >> 31) << i;
                pk[e][i] = (__bf16)xv;
            }
            by[e] = bb;
        }
        const int sh = chg*8;
        sb0 = ((unsigned long long)by[0]) << sh;
        sb1 = ((unsigned long long)by[1]) << sh;
        sb2 = ((unsigned long long)by[2]) << sh;
        sb3 = ((unsigned long long)by[3]) << sh;
    }
    // OR-tree over the 8 ch-groups (lane bits 3..5)
    #pragma unroll
    for (int m = 8; m <= 32; m <<= 1) {
        sb0 |= __shfl_xor(sb0, m);
        sb1 |= __shfl_xor(sb1, m);
        sb2 |= __shfl_xor(sb2, m);
        sb3 |= __shfl_xor(sb3, m);
    }

    // ---- Skip-conv MFMAs in two 16-px passes through per-wave LDS exchange.
    // xsl layout: [8 slot][16 px][8] u16 (slot = ch octet).
    unsigned short* xsl = (unsigned short*)((char*)planes + w*2048);
    #pragma unroll
    for (int g = 0; g < 2; ++g) {
        if ((pxg >> 2) == g) {
            const int px16 = (pxg & 3)*4;
            *(bf16x8*)&xsl[(chg*16 + px16 + 0)*8] = pk[0];
            *(bf16x8*)&xsl[(chg*16 + px16 + 1)*8] = pk[1];
            *(bf16x8*)&xsl[(chg*16 + px16 + 2)*8] = pk[2];
            *(bf16x8*)&xsl[(chg*16 + px16 + 3)*8] = pk[3];
        }
        lds_fence();   // wave-synchronous: writes visible before reads
        #pragma unroll
        for (int p = 0; p < 2; ++p) {
            // B-frag: slot p*4 + lg (ch p*32 + lg*8 ..+7), px = lr (actual px g*16+lr)
            bf16x8 bx = *(const bf16x8*)&xsl[((p*4 + lg)*16 + lr)*8];
            #pragma unroll
            for (int rt = 0; rt < 4; ++rt) {
                bf16x8 sa = *(const bf16x8*)&swfrag[((rt*2 + p)*64 + l)*8];
                skacc[rt][g] = __builtin_amdgcn_mfma_f32_16x16x32_bf16(
                    sa, bx, skacc[rt][g], 0, 0, 0);
            }
        }
        lds_fence();   // reads done before next pass overwrites
    }
    __syncthreads();   // all waves done with the exchange overlay

    // ---- Interior sign planes: lane writes px = pxg*4 + (chg&3), 2 slots.
    {
        const int e = chg & 3;
        unsigned long long mysb = (e == 0) ? sb0 : (e == 1) ? sb1 : (e == 2) ? sb2 : sb3;
        const int px = pxg*4 + e;
        const int sbase = (chg >> 2)*2;
        #pragma unroll
        for (int sp = 0; sp < 2; ++sp) {
            const int s = sbase + sp;
            unsigned int slice = (unsigned int)(mysb >> (s*16)) & 0xffffu;
            i32x4 dw;
            dw[0] = expand4(slice & 15);
            dw[1] = expand4((slice >> 4) & 15);
            dw[2] = expand4((slice >> 8) & 15);
            dw[3] = expand4((slice >> 12) & 15);
            *(i32x4*)&planes[(((w + 1)*4 + s)*34 + px + 1)*16] = dw;
        }
    }

    // ---- Halo planes: 84 px x 2 ch-halves = 168 jobs (scalar path).
    if (tid < 168) {
        const int idx = tid >> 1, hh = tid & 1;
        int r, c;
        if (idx < 34)      { r = 0;        c = idx;      }
        else if (idx < 68) { r = 9;        c = idx - 34; }
        else if (idx < 76) { r = idx - 67; c = 0;        }   // r = 1..8
        else               { r = idx - 75; c = 33;       }   // r = 1..8
        const int hg = byp*8 + r - 1, wg = px0 + c - 1;
        const bool inb = (hg >= 0 && hg < 256 && wg >= 0 && wg < 256);
        #pragma unroll
        for (int p = 0; p < 2; ++p) {
            i32x4 dw = (i32x4){0, 0, 0, 0};          // OOB => 0 bytes = exact zero-pad
            if (inb) {
                unsigned int bb = 0;
                const int po = hg*256 + wg;
                #pragma unroll
                for (int j = 0; j < 16; ++j) {
                    const int ch = p*32 + hh*16 + j;
                    bb |= (__float_as_uint(xb[(size_t)ch*HW + po] + mb[ch]) >> 31) << j;
                }
                dw[0] = expand4(bb & 15);
                dw[1] = expand4((bb >> 4) & 15);
                dw[2] = expand4((bb >> 8) & 15);
                dw[3] = expand4((bb >> 12) & 15);
            }
            *(i32x4*)&planes[((r*4 + (hh + 2*p))*34 + c)*16] = dw;
        }
    }
    __syncthreads();

    // ---- Phase C: binary conv via i8 MFMA; A expanded from packed bits per tap.
    const int prow_base = ((w*4 + lg)*34 + lr)*16;
    float* outp = out + (size_t)b*64*HW + h0*256 + px0;

    #pragma unroll
    for (int rt = 0; rt < 4; ++rt) {
        // this lane's packed A row: 5 dwords, stride 20 B (bank-conflict-free)
        const unsigned int* arow = (const unsigned int*)&Abits[(rt*64 + l)*10];
        unsigned int ad[5];
        #pragma unroll
        for (int k = 0; k < 5; ++k) ad[k] = arow[k];

        i32x4 bacc0 = (i32x4){0,0,0,0}, bacc1 = (i32x4){0,0,0,0};
        #pragma unroll
        for (int t = 0; t < 9; ++t) {
            const int dr = t / 3, dc = t % 3;
            const unsigned int tb = (ad[t >> 1] >> ((t & 1)*16)) & 0xffffu;
            i32x4 a;
            a[0] = expand4(tb & 15);
            a[1] = expand4((tb >> 4) & 15);
            a[2] = expand4((tb >> 8) & 15);
            a[3] = expand4((tb >> 12) & 15);
            i32x4 b0 = *(const i32x4*)&planes[prow_base + dr*(4*34*16) + dc*16];
            i32x4 b1 = *(const i32x4*)&planes[prow_base + dr*(4*34*16) + dc*16 + 256];
            bacc0 = __builtin_amdgcn_mfma_i32_16x16x64_i8(a, b0, bacc0, 0, 0, 0);
            bacc1 = __builtin_amdgcn_mfma_i32_16x16x64_i8(a, b1, bacc1, 0, 0, 0);
        }
        #pragma unroll
        for (int qi = 0; qi < 4; ++qi) {
            const int o = rt*16 + lg*4 + qi;
            f32x4 c4 = *(const f32x4*)&cons[o*4];   // (sf, pb0, aP, pb1+skip_b)
            {
                float tv = fmaf(c4[0], (float)bacc0[qi], c4[1]);
                tv = fmaxf(tv, 0.f) + c4[2]*fminf(tv, 0.f);
                outp[(size_t)o*HW + lr] = tv + c4[3] + skacc[rt][0][qi];
            }
            {
                float tv = fmaf(c4[0], (float)bacc1[qi], c4[1]);
                tv = fmaxf(tv, 0.f) + c4[2]*fminf(tv, 0.f);
                outp[(size_t)o*HW + 16 + lr] = tv + c4[3] + skacc[rt][1][qi];
            }
        }
    }
}

extern "C" void kernel_launch(void* const* d_in, const int* in_sizes, int n_in,
                              void* d_out, int out_size, void* d_ws, size_t ws_size,
                              hipStream_t stream) {
    const float* x      = (const float*)d_in[0];
    const float* mb     = (const float*)d_in[1];
    const float* weight = (const float*)d_in[2];
    const float* pb0    = (const float*)d_in[3];
    const float* pw     = (const float*)d_in[4];
    const float* pb1    = (const float*)d_in[5];
    const float* skw    = (const float*)d_in[6];
    const float* skb    = (const float*)d_in[7];
    float* out = (float*)d_out;

    char* ws = (char*)d_ws;
    unsigned short* abits  = (unsigned short*)ws;              // 5120 B
    unsigned short* swfrag = (unsigned short*)(ws + 5120);     // 8192 B
    float*          consg  = (float*)(ws + 13312);             // 1024 B (total 14336)

    hipLaunchKernelGGL(bq_prep_kernel, dim3(1), dim3(576), 0, stream,
                       weight, pb0, pw, pb1, skb, skw, abits, swfrag, consg);
    hipLaunchKernelGGL(bq_main_kernel, dim3(2048), dim3(512), 0, stream,
                       x, mb, abits, swfrag, consg, out);
}